// Round 1
// baseline (17090.967 us; speedup 1.0000x reference)
//
#include <hip/hip_runtime.h>
#include <hip/hip_bf16.h>

#define DH 64
#define DM 256

__device__ __forceinline__ float tanh_fast(float y) {
    // tanh(y) = 1 - 2/(exp(2y)+1); correct limits at +/-inf
    float e = __expf(2.0f * y);
    return 1.0f - 2.0f / (e + 1.0f);
}

__device__ __forceinline__ float sigmoid_fast(float x) {
    return 1.0f / (1.0f + __expf(-x));
}

// ---------------------------------------------------------------------------
// Kernel A: u[t][0..63] = phi[t]·thetaQ[h], u[t][64..127] = phi[t]·thetaK[h]
// Tile: 32 t-rows x 128 h-cols per 256-thread block; K chunks of 32 with
// register-prefetch double buffering. fp32 vector FMA (no fp32 MFMA on CDNA4).
// ---------------------------------------------------------------------------
__global__ __launch_bounds__(256) void proj_kernel(
    const float* __restrict__ phi,   // [T][dphi]
    const float* __restrict__ thK,   // [64][dphi]
    const float* __restrict__ thQ,   // [64][dphi]
    float* __restrict__ u,           // [T][128]
    int dphi)
{
    const int tid  = threadIdx.x;
    const int th32 = tid & 31;       // h-group
    const int tt8  = tid >> 5;       // t-group
    const int t0   = tt8 * 4;
    const int h0   = th32 * 4;
    const int T0   = blockIdx.x * 32;

    __shared__ float sPhiT[32][36];   // [k][t], +4 pad keeps float4 alignment
    __shared__ float sThT[32][128];   // [k][h]

    // staging assignments
    const int h   = tid >> 1;                 // 0..127
    const int ko  = (tid & 1) * 16;           // 0 or 16
    const float* trow = (h < 64) ? (thQ + (size_t)h * dphi)
                                 : (thK + (size_t)(h - 64) * dphi);
    const int tr  = tid >> 3;                 // 0..31
    const int k4p = (tid & 7) * 4;            // 0,4,...,28

    float4 pv, tv0, tv1, tv2, tv3;
    // prologue: load chunk 0
    pv  = *(const float4*)&phi[(size_t)(T0 + tr) * dphi + k4p];
    tv0 = *(const float4*)&trow[ko + 0];
    tv1 = *(const float4*)&trow[ko + 4];
    tv2 = *(const float4*)&trow[ko + 8];
    tv3 = *(const float4*)&trow[ko + 12];

    float acc[4][4];
    #pragma unroll
    for (int i = 0; i < 4; ++i)
        #pragma unroll
        for (int jj = 0; jj < 4; ++jj) acc[i][jj] = 0.0f;

    const int NC = dphi / 32;
    for (int c = 0; c < NC; ++c) {
        __syncthreads();   // previous chunk's LDS reads done
        // stage regs -> LDS (transposed)
        sPhiT[k4p + 0][tr] = pv.x;
        sPhiT[k4p + 1][tr] = pv.y;
        sPhiT[k4p + 2][tr] = pv.z;
        sPhiT[k4p + 3][tr] = pv.w;
        sThT[ko +  0][h] = tv0.x;  sThT[ko +  1][h] = tv0.y;
        sThT[ko +  2][h] = tv0.z;  sThT[ko +  3][h] = tv0.w;
        sThT[ko +  4][h] = tv1.x;  sThT[ko +  5][h] = tv1.y;
        sThT[ko +  6][h] = tv1.z;  sThT[ko +  7][h] = tv1.w;
        sThT[ko +  8][h] = tv2.x;  sThT[ko +  9][h] = tv2.y;
        sThT[ko + 10][h] = tv2.z;  sThT[ko + 11][h] = tv2.w;
        sThT[ko + 12][h] = tv3.x;  sThT[ko + 13][h] = tv3.y;
        sThT[ko + 14][h] = tv3.z;  sThT[ko + 15][h] = tv3.w;
        __syncthreads();
        // prefetch next chunk into registers (overlaps compute below)
        if (c + 1 < NC) {
            const int kb = (c + 1) * 32;
            pv  = *(const float4*)&phi[(size_t)(T0 + tr) * dphi + kb + k4p];
            tv0 = *(const float4*)&trow[kb + ko + 0];
            tv1 = *(const float4*)&trow[kb + ko + 4];
            tv2 = *(const float4*)&trow[kb + ko + 8];
            tv3 = *(const float4*)&trow[kb + ko + 12];
        }
        // compute chunk c
        #pragma unroll 8
        for (int k = 0; k < 32; ++k) {
            float4 ph = *(const float4*)&sPhiT[k][t0];
            float4 th = *(const float4*)&sThT[k][h0];
            acc[0][0] = fmaf(ph.x, th.x, acc[0][0]);
            acc[0][1] = fmaf(ph.x, th.y, acc[0][1]);
            acc[0][2] = fmaf(ph.x, th.z, acc[0][2]);
            acc[0][3] = fmaf(ph.x, th.w, acc[0][3]);
            acc[1][0] = fmaf(ph.y, th.x, acc[1][0]);
            acc[1][1] = fmaf(ph.y, th.y, acc[1][1]);
            acc[1][2] = fmaf(ph.y, th.z, acc[1][2]);
            acc[1][3] = fmaf(ph.y, th.w, acc[1][3]);
            acc[2][0] = fmaf(ph.z, th.x, acc[2][0]);
            acc[2][1] = fmaf(ph.z, th.y, acc[2][1]);
            acc[2][2] = fmaf(ph.z, th.z, acc[2][2]);
            acc[2][3] = fmaf(ph.z, th.w, acc[2][3]);
            acc[3][0] = fmaf(ph.w, th.x, acc[3][0]);
            acc[3][1] = fmaf(ph.w, th.y, acc[3][1]);
            acc[3][2] = fmaf(ph.w, th.z, acc[3][2]);
            acc[3][3] = fmaf(ph.w, th.w, acc[3][3]);
        }
    }
    // epilogue
    #pragma unroll
    for (int i = 0; i < 4; ++i) {
        float4 o;
        o.x = acc[i][0]; o.y = acc[i][1]; o.z = acc[i][2]; o.w = acc[i][3];
        *(float4*)&u[(size_t)(T0 + t0 + i) * 128 + h0] = o;
    }
}

// ---------------------------------------------------------------------------
// Kernel B: sequential TTT scan. One 256-thread block; thread j owns W1[:,j]
// in registers. u broadcast via wave-uniform (scalar) loads. One barrier/step
// (partials double-buffered in LDS).
// ---------------------------------------------------------------------------
__global__ __launch_bounds__(256, 1) void ttt_scan(
    const float* __restrict__ u,       // [T][128]: 0..63 = u_q, 64..127 = u_k
    const float* __restrict__ C_seq,   // [T]
    const float* __restrict__ W10,     // [64][256]
    const float* __restrict__ b10,     // [256]
    const float* __restrict__ W20,     // [256]
    const float* __restrict__ b20,     // [1]
    const float* __restrict__ log_eta, // [1]
    float* __restrict__ out,           // [T+1]: scores then loss
    int T)
{
    const int j    = threadIdx.x;
    const int lane = j & 63;
    const int wv   = j >> 6;

    float w1[DH];
    #pragma unroll
    for (int i = 0; i < DH; ++i) w1[i] = W10[i * DM + j];
    float b1j = b10[j];
    float w2j = W20[j];
    float b2  = b20[0];
    const float eta = __expf(log_eta[0]);
    float loss = 0.0f;

    __shared__ float pQ[2][4];
    __shared__ float pK[2][4];

    for (int t = 0; t < T; ++t) {
        const float* ut = u + (size_t)t * 128;

        // two matvecs against register-resident W1 column
        float zq = b1j, zk = b1j;
        #pragma unroll
        for (int i = 0; i < DH; ++i) {
            float uq = ut[i];
            float uk = ut[DH + i];
            zq = fmaf(uq, w1[i], zq);
            zk = fmaf(uk, w1[i], zk);
        }

        // gelu(zq) (score path) and gelu(zk) (update path)
        float tq = tanh_fast(0.79788456f * zq * fmaf(0.044715f, zq * zq, 1.0f));
        float aq = 0.5f * zq * (1.0f + tq);
        float tk = tanh_fast(0.79788456f * zk * fmaf(0.044715f, zk * zk, 1.0f));
        float x2 = 0.5f * zk * (1.0f + tk);

        float pq = aq * w2j;
        float pk = x2 * w2j;
        // intra-wave reductions (64 lanes)
        #pragma unroll
        for (int off = 32; off > 0; off >>= 1) {
            pq += __shfl_xor(pq, off);
            pk += __shfl_xor(pk, off);
        }
        const int pb = t & 1;
        if (lane == 0) { pQ[pb][wv] = pq; pK[pb][wv] = pk; }
        __syncthreads();
        float zs = pQ[pb][0] + pQ[pb][1] + pQ[pb][2] + pQ[pb][3] + b2;
        float zp = pK[pb][0] + pK[pb][1] + pK[pb][2] + pK[pb][3] + b2;

        float s    = sigmoid_fast(zs);
        float pred = sigmoid_fast(zp);
        float dZ2  = 2.0f * pred * pred * (1.0f - pred);
        // gelu_bwd(zk), reusing tk
        float gb  = 0.5f * zk * ((1.0f - tk * tk) * fmaf(0.1070322243f, zk * zk, 0.79788456f))
                  + 0.5f * (1.0f + tk);
        float dZ1 = dZ2 * w2j * gb;

        // fast-weight updates (W(t) -> W(t+1))
        float e1 = eta * dZ1;
        #pragma unroll
        for (int i = 0; i < DH; ++i) {
            w1[i] = fmaf(-e1, ut[DH + i], w1[i]);
        }
        b1j -= e1;
        w2j = fmaf(-eta * dZ2, x2, w2j);
        b2 -= eta * dZ2;

        // score + loss
        float c = C_seq[t];
        if (j == 0) out[t] = s;
        float d = s - c;
        loss = fmaf(d, d, loss);
    }
    if (j == 0) out[T] = loss;
}

// ---------------------------------------------------------------------------
extern "C" void kernel_launch(void* const* d_in, const int* in_sizes, int n_in,
                              void* d_out, int out_size, void* d_ws, size_t ws_size,
                              hipStream_t stream) {
    const float* phi     = (const float*)d_in[0];
    const float* C_seq   = (const float*)d_in[1];
    const float* thK     = (const float*)d_in[2];
    const float* thQ     = (const float*)d_in[3];
    const float* W10     = (const float*)d_in[4];
    const float* b10     = (const float*)d_in[5];
    const float* W20     = (const float*)d_in[6];
    const float* b20     = (const float*)d_in[7];
    const float* log_eta = (const float*)d_in[8];

    const int T    = in_sizes[1];          // 8192
    const int dphi = in_sizes[0] / T;      // 4096

    float* u = (float*)d_ws;               // [T][128] = 4 MB

    proj_kernel<<<T / 32, 256, 0, stream>>>(phi, thK, thQ, u, dphi);
    ttt_scan<<<1, 256, 0, stream>>>(u, C_seq, W10, b10, W20, b20, log_eta,
                                    (float*)d_out, T);
}